// Round 1
// baseline (1093.737 us; speedup 1.0000x reference)
//
#include <hip/hip_runtime.h>
#include <math.h>

// GaussianScaleReadout: y[b,o] = sum_k alpha[b,k] * (sum_c h[b,c,k]*w[k,o,c] + bias[k,o])
// Memory-bound on h (512 MiB, read exactly once). v2: software-pipelined grid-stride
// loop. Each wave handles 2 queries per iteration (8 KiB, 8 independent dwordx4 loads
// + 1 float4 cell load issued FIRST so softmax really sits under the load shadow).
// Next group's loads are issued before the current group's reduce/store, double-buffered
// in registers, so the memory pipe never goes idle during the shuffle-reduce tail.
// VGPR target ~160 -> 3 waves/SIMD (vs ~190/2 in v1).
//
// Index algebra (h inner layout [c,k], k fastest; float4 j = i*64+lane of the
// 2-query block): q = i>>2 (query), k = (lane&1)*4+e, c = (i&3)*32+(lane>>1).
// Weights (12 KiB) live in 48 VGPRs per lane, loaded once per wave.

#define C_H   128
#define KSC   8

constexpr int NBLOCKS  = 2048;   // grid-stride
constexpr int NTHREADS = 256;    // 4 waves/block
constexpr int NWAVES   = NBLOCKS * NTHREADS / 64;  // 8192

__global__ __launch_bounds__(NTHREADS, 3)
void gsr_kernel(const float* __restrict__ h,      // [BQ, C_H, K]
                const float* __restrict__ cell,   // [BQ, 2]
                const float* __restrict__ w,      // [K, 3, C_H]
                const float* __restrict__ bias,   // [K, 3]
                float* __restrict__ out,          // [BQ, 3]
                int bq)
{
    const int lane   = threadIdx.x & 63;
    const int waveId = blockIdx.x * (NTHREADS / 64) + (threadIdx.x >> 6);

    const int ngrp = bq >> 1;            // groups of 2 queries
    if (waveId >= ngrp) return;

    // ---- one-time per-wave weight preload into registers ----
    const int kbase = (lane & 1) * 4;   // this lane's k-subset base (0 or 4)
    const int chalf = lane >> 1;
    float wreg[4][4][3];                // [i&3][e][o]
    #pragma unroll
    for (int i4 = 0; i4 < 4; ++i4) {
        #pragma unroll
        for (int e = 0; e < 4; ++e) {
            const int k = kbase + e;
            const int c = i4 * 32 + chalf;
            #pragma unroll
            for (int o = 0; o < 3; ++o)
                wreg[i4][e][o] = w[k * (3*C_H) + o * C_H + c];
        }
    }
    // bias fragments: lane 0 covers k=0..3, lane 1 covers k=4..7, others zero;
    // the cross-lane reduction sums them exactly once.
    float breg[4][3];
    #pragma unroll
    for (int e = 0; e < 4; ++e)
        #pragma unroll
        for (int o = 0; o < 3; ++o)
            breg[e][o] = (lane < 2) ? bias[(kbase + e) * 3 + o] : 0.0f;

    const float inv_two_sigma_sq = 0.78125f;             // 1 / (2*0.8^2)
    const float log_2_over_inp   = -4.8520302639196171f; // log(2/256)
    const float seven_over_log30 = 2.0580814087539097f;  // 7 / log(30)

    const float4* cell4 = (const float4*)cell;   // one float4 = cells of 2 queries

    // ---- pipeline stages ----
    auto issue = [&](int g, float4& cv, float4 (&hv)[8]) {
        // cell load FIRST: it is then the oldest outstanding load, so consuming it
        // in softmax needs only a counted vmcnt that leaves all h-loads in flight.
        cv = cell4[g];
        const float4* hp = (const float4*)(h + (size_t)g * (2 * C_H * KSC));
        #pragma unroll
        for (int i = 0; i < 8; ++i)
            hv[i] = hp[i * 64 + lane];
    };

    auto compute = [&](int g, const float4& cv, const float4 (&hv)[8]) {
        float al[2][4];   // [q][e]: alpha for k = kbase+e
        float acc[2][3];
        #pragma unroll
        for (int q = 0; q < 2; ++q) {
            const float cx = q ? cv.z : cv.x;
            const float cy = q ? cv.w : cv.y;
            const float geo   = fmaxf(sqrtf(cx * cy), 1e-10f);
            const float log_s = log_2_over_inp - __logf(geo);
            float tau = fminf(fmaxf(seven_over_log30 * log_s, 0.0f), 7.0f);

            float ek[8], s = 0.0f;
            #pragma unroll
            for (int k = 0; k < 8; ++k) {
                const float d = (float)k - tau;
                ek[k] = __expf(-d * d * inv_two_sigma_sq);
                s += ek[k];
            }
            const float inv = 1.0f / s;
            #pragma unroll
            for (int e = 0; e < 4; ++e)
                al[q][e] = ((lane & 1) ? ek[4 + e] : ek[e]) * inv;

            // bias into accumulator init (zero except lanes 0/1)
            #pragma unroll
            for (int o = 0; o < 3; ++o) {
                acc[q][o] = al[q][0] * breg[0][o];
                #pragma unroll
                for (int e = 1; e < 4; ++e)
                    acc[q][o] = fmaf(al[q][e], breg[e][o], acc[q][o]);
            }
        }

        // ---- accumulate (progressive vmcnt waits on the OLDER buffer only) ----
        #pragma unroll
        for (int i = 0; i < 8; ++i) {
            const int q  = i >> 2;
            const int i4 = i & 3;
            const float he[4] = {hv[i].x, hv[i].y, hv[i].z, hv[i].w};
            #pragma unroll
            for (int e = 0; e < 4; ++e) {
                const float ha = he[e] * al[q][e];
                #pragma unroll
                for (int o = 0; o < 3; ++o)
                    acc[q][o] = fmaf(ha, wreg[i4][e][o], acc[q][o]);
            }
        }

        // ---- 6 independent butterfly reductions over 64 lanes ----
        // (next group's 8 loads are already in flight while this runs)
        #pragma unroll
        for (int off = 32; off > 0; off >>= 1) {
            #pragma unroll
            for (int q = 0; q < 2; ++q) {
                acc[q][0] += __shfl_xor(acc[q][0], off, 64);
                acc[q][1] += __shfl_xor(acc[q][1], off, 64);
                acc[q][2] += __shfl_xor(acc[q][2], off, 64);
            }
        }

        // ---- lane 0 stores 6 contiguous floats (24B-aligned -> 3 x float2) ----
        if (lane == 0) {
            float2* op = (float2*)(out + (size_t)g * 6);
            op[0] = make_float2(acc[0][0], acc[0][1]);
            op[1] = make_float2(acc[0][2], acc[1][0]);
            op[2] = make_float2(acc[1][1], acc[1][2]);
        }
    };

    // ---- double-buffered software pipeline over the grid-stride loop ----
    float4 cva, cvb;
    float4 hva[8], hvb[8];

    int g = waveId;
    issue(g, cva, hva);
    for (;;) {
        int gn = g + NWAVES;
        if (gn < ngrp) {
            issue(gn, cvb, hvb);      // prefetch n+1 before consuming n
            compute(g, cva, hva);
            g = gn;
        } else {
            compute(g, cva, hva);     // epilogue: nothing left to prefetch
            break;
        }
        gn = g + NWAVES;
        if (gn < ngrp) {
            issue(gn, cva, hva);
            compute(g, cvb, hvb);
            g = gn;
        } else {
            compute(g, cvb, hvb);
            break;
        }
    }
}

extern "C" void kernel_launch(void* const* d_in, const int* in_sizes, int n_in,
                              void* d_out, int out_size, void* d_ws, size_t ws_size,
                              hipStream_t stream) {
    const float* h    = (const float*)d_in[0];
    const float* cell = (const float*)d_in[1];
    const float* w    = (const float*)d_in[2];
    const float* bias = (const float*)d_in[3];
    float* out = (float*)d_out;
    const int bq = in_sizes[0] / (C_H * KSC);

    gsr_kernel<<<NBLOCKS, NTHREADS, 0, stream>>>(h, cell, w, bias, out, bq);
}

// Round 2
// 854.974 us; speedup vs baseline: 1.2793x; 1.2793x over previous
//
#include <hip/hip_runtime.h>
#include <math.h>

// GaussianScaleReadout: y[b,o] = sum_k alpha[b,k] * (sum_c h[b,c,k]*w[k,o,c] + bias[k,o])
// Memory-bound on h (512 MiB, read exactly once). v3: register double-buffered
// software pipeline with NO arrays-by-reference (v2's lambda captures defeated SROA
// and PromoteAlloca pushed the buffers into LDS/scratch: LDS_Block_Size=16384,
// 1.1e7 bank conflicts, 354 MB scratch writes). All pipeline state is token-pasted
// scalar float4s -> guaranteed registers. sched_barrier(0) after each load batch
// prevents the scheduler from sinking loads toward uses under register pressure
// (the suspected cause of v1's 1.6 TB/s). Cell load issued FIRST in each batch so
// softmax consumes it with a counted vmcnt that leaves all h-loads in flight.
//
// Index algebra (h inner layout [c,k], k fastest; float4 j = i*64+lane of the
// 2-query block): q = i>>2, k = (lane&1)*4+e, c = (i&3)*32+(lane>>1).
// Weights (12 KiB) live in 48 VGPRs per lane, loaded once per wave.

#define C_H   128
#define KSC   8

constexpr int NBLOCKS  = 2048;   // grid-stride
constexpr int NTHREADS = 256;    // 4 waves/block
constexpr int NWAVES   = NBLOCKS * NTHREADS / 64;  // 8192

// ---- load one 2-query batch into buffer S (cell first, then 8x dwordx4), pinned ----
#define ISSUE(S, g_) do {                                                     \
    cv##S = cell4[g_];                                                        \
    const float4* hp_ = (const float4*)(h + (size_t)(g_) * (2 * C_H * KSC));  \
    h##S##0 = hp_[0*64 + lane];  h##S##1 = hp_[1*64 + lane];                  \
    h##S##2 = hp_[2*64 + lane];  h##S##3 = hp_[3*64 + lane];                  \
    h##S##4 = hp_[4*64 + lane];  h##S##5 = hp_[5*64 + lane];                  \
    h##S##6 = hp_[6*64 + lane];  h##S##7 = hp_[7*64 + lane];                  \
    __builtin_amdgcn_sched_barrier(0);                                        \
} while (0)

// ---- accumulate one float4 (4 consecutive k at this lane's (c, khalf)) ----
#define ACC4(hv_, q_, i4_) do {                                               \
    const float he_[4] = {hv_.x, hv_.y, hv_.z, hv_.w};                        \
    _Pragma("unroll") for (int e = 0; e < 4; ++e) {                           \
        const float ha_ = he_[e] * al[q_][e];                                 \
        _Pragma("unroll") for (int o = 0; o < 3; ++o)                         \
            acc[q_][o] = fmaf(ha_, wreg[i4_][e][o], acc[q_][o]);              \
    }                                                                         \
} while (0)

// ---- consume buffer S for group g_: softmax, accumulate, reduce, store ----
#define COMPUTE(S, g_) do {                                                   \
    float al[2][4];                                                           \
    float acc[2][3];                                                          \
    _Pragma("unroll") for (int q = 0; q < 2; ++q) {                           \
        const float cx_ = q ? cv##S.z : cv##S.x;                              \
        const float cy_ = q ? cv##S.w : cv##S.y;                              \
        const float geo_   = fmaxf(sqrtf(cx_ * cy_), 1e-10f);                 \
        const float log_s_ = log_2_over_inp - __logf(geo_);                   \
        float tau_ = fminf(fmaxf(seven_over_log30 * log_s_, 0.0f), 7.0f);     \
        float ek_[8], s_ = 0.0f;                                              \
        _Pragma("unroll") for (int k = 0; k < 8; ++k) {                       \
            const float d_ = (float)k - tau_;                                 \
            ek_[k] = __expf(-d_ * d_ * inv_two_sigma_sq);                     \
            s_ += ek_[k];                                                     \
        }                                                                     \
        const float inv_ = 1.0f / s_;                                         \
        _Pragma("unroll") for (int e = 0; e < 4; ++e)                         \
            al[q][e] = ((lane & 1) ? ek_[4 + e] : ek_[e]) * inv_;             \
        _Pragma("unroll") for (int o = 0; o < 3; ++o) {                       \
            acc[q][o] = al[q][0] * breg[0][o];                                \
            _Pragma("unroll") for (int e = 1; e < 4; ++e)                     \
                acc[q][o] = fmaf(al[q][e], breg[e][o], acc[q][o]);            \
        }                                                                     \
    }                                                                         \
    ACC4(h##S##0, 0, 0);  ACC4(h##S##1, 0, 1);                                \
    ACC4(h##S##2, 0, 2);  ACC4(h##S##3, 0, 3);                                \
    ACC4(h##S##4, 1, 0);  ACC4(h##S##5, 1, 1);                                \
    ACC4(h##S##6, 1, 2);  ACC4(h##S##7, 1, 3);                                \
    _Pragma("unroll") for (int off = 32; off > 0; off >>= 1) {                \
        _Pragma("unroll") for (int q = 0; q < 2; ++q) {                       \
            acc[q][0] += __shfl_xor(acc[q][0], off, 64);                      \
            acc[q][1] += __shfl_xor(acc[q][1], off, 64);                      \
            acc[q][2] += __shfl_xor(acc[q][2], off, 64);                      \
        }                                                                     \
    }                                                                         \
    if (lane == 0) {                                                          \
        float2* op_ = (float2*)(out + (size_t)(g_) * 6);                      \
        op_[0] = make_float2(acc[0][0], acc[0][1]);                           \
        op_[1] = make_float2(acc[0][2], acc[1][0]);                           \
        op_[2] = make_float2(acc[1][1], acc[1][2]);                           \
    }                                                                         \
} while (0)

__global__ __launch_bounds__(NTHREADS, 2)
void gsr_kernel(const float* __restrict__ h,      // [BQ, C_H, K]
                const float* __restrict__ cell,   // [BQ, 2]
                const float* __restrict__ w,      // [K, 3, C_H]
                const float* __restrict__ bias,   // [K, 3]
                float* __restrict__ out,          // [BQ, 3]
                int bq)
{
    const int lane   = threadIdx.x & 63;
    const int waveId = blockIdx.x * (NTHREADS / 64) + (threadIdx.x >> 6);

    const int ngrp = bq >> 1;            // groups of 2 queries
    if (waveId >= ngrp) return;

    // ---- one-time per-wave weight preload into registers ----
    const int kbase = (lane & 1) * 4;   // this lane's k-subset base (0 or 4)
    const int chalf = lane >> 1;
    float wreg[4][4][3];                // [i&3][e][o]
    #pragma unroll
    for (int i4 = 0; i4 < 4; ++i4) {
        #pragma unroll
        for (int e = 0; e < 4; ++e) {
            const int k = kbase + e;
            const int c = i4 * 32 + chalf;
            #pragma unroll
            for (int o = 0; o < 3; ++o)
                wreg[i4][e][o] = w[k * (3*C_H) + o * C_H + c];
        }
    }
    // bias fragments: lane 0 covers k=0..3, lane 1 covers k=4..7, others zero;
    // the cross-lane reduction sums them exactly once.
    float breg[4][3];
    #pragma unroll
    for (int e = 0; e < 4; ++e)
        #pragma unroll
        for (int o = 0; o < 3; ++o)
            breg[e][o] = (lane < 2) ? bias[(kbase + e) * 3 + o] : 0.0f;

    const float inv_two_sigma_sq = 0.78125f;             // 1 / (2*0.8^2)
    const float log_2_over_inp   = -4.8520302639196171f; // log(2/256)
    const float seven_over_log30 = 2.0580814087539097f;  // 7 / log(30)

    const float4* cell4 = (const float4*)cell;   // one float4 = cells of 2 queries

    // ---- pipeline state: pure scalars, guaranteed registers ----
    float4 cvA, cvB;
    float4 hA0, hA1, hA2, hA3, hA4, hA5, hA6, hA7;
    float4 hB0, hB1, hB2, hB3, hB4, hB5, hB6, hB7;

    int g  = waveId;
    ISSUE(A, g);
    int gn = g + NWAVES;
    while (true) {
        if (gn >= ngrp) { COMPUTE(A, g); break; }
        ISSUE(B, gn);                 // batch n+1 in flight across compute of n
        COMPUTE(A, g);
        g = gn;  gn += NWAVES;
        if (gn >= ngrp) { COMPUTE(B, g); break; }
        ISSUE(A, gn);
        COMPUTE(B, g);
        g = gn;  gn += NWAVES;
    }
}

extern "C" void kernel_launch(void* const* d_in, const int* in_sizes, int n_in,
                              void* d_out, int out_size, void* d_ws, size_t ws_size,
                              hipStream_t stream) {
    const float* h    = (const float*)d_in[0];
    const float* cell = (const float*)d_in[1];
    const float* w    = (const float*)d_in[2];
    const float* bias = (const float*)d_in[3];
    float* out = (float*)d_out;
    const int bq = in_sizes[0] / (C_H * KSC);

    gsr_kernel<<<NBLOCKS, NTHREADS, 0, stream>>>(h, cell, w, bias, out, bq);
}

// Round 3
// 710.912 us; speedup vs baseline: 1.5385x; 1.2026x over previous
//
#include <hip/hip_runtime.h>
#include <math.h>

// GaussianScaleReadout: y[b,o] = sum_k alpha[b,k] * (sum_c h[b,c,k]*w[k,o,c] + bias[k,o])
// Memory-bound on h (512 MiB, read exactly once). v4: ZERO local arrays.
// v2/v3 post-mortem: every version carrying ANY small local array (wreg[4][4][3],
// ek[8], al[][], acc[][]) shipped with LDS_Block_Size=16384 + ~100-350 MB of
// phantom scratch writes -> dependency chains on L2-latency reloads -> each wave's
// loads in flight only ~4% of the time -> 1.6 TB/s. Here every value is a named
// scalar/float4: 12 float4 weights, ek0..7, al0..3, acc0..2, bias in SGPRs via
// readfirstlane. One query per wave per iteration (4 KB = 4 dwordx4 + 1 float2
// cell, cell first), register double-buffered across grid-stride iterations with
// sched_barrier(0) pinning, so batch n+1 stays in flight through compute of n
// (counted vmcnt). Target VGPR ~115 -> 4 waves/SIMD.
//
// Index algebra (h inner layout [c,k], k fastest; float4 j = i*64+lane):
// k = (lane&1)*4+e, c = i*32+(lane>>1), i = 0..3.

#define C_H   128
#define KSC   8

constexpr int NBLOCKS  = 2048;   // grid-stride
constexpr int NTHREADS = 256;    // 4 waves/block
constexpr int NWAVES   = NBLOCKS * NTHREADS / 64;  // 8192

__device__ __forceinline__ float rfl(float x) {
    return __uint_as_float(__builtin_amdgcn_readfirstlane(__float_as_uint(x)));
}

// ---- load one 1-query batch into buffer S (cell first, then 4x dwordx4), pinned ----
#define ISSUE(S, g_) do {                                                     \
    cv##S = cell2[g_];                                                        \
    const float4* hp_ = (const float4*)(h + (size_t)(g_) * (C_H * KSC));      \
    h##S##0 = hp_[  0 + lane];  h##S##1 = hp_[ 64 + lane];                    \
    h##S##2 = hp_[128 + lane];  h##S##3 = hp_[192 + lane];                    \
    __builtin_amdgcn_sched_barrier(0);                                        \
} while (0)

// ---- accumulate one float4 against weight plane i ----
#define ACCI(hv_, i_) do {                                                    \
    float ha_;                                                                \
    ha_ = hv_.x * al0; acc0 = fmaf(ha_, w0##i_.x, acc0);                      \
                       acc1 = fmaf(ha_, w1##i_.x, acc1);                      \
                       acc2 = fmaf(ha_, w2##i_.x, acc2);                      \
    ha_ = hv_.y * al1; acc0 = fmaf(ha_, w0##i_.y, acc0);                      \
                       acc1 = fmaf(ha_, w1##i_.y, acc1);                      \
                       acc2 = fmaf(ha_, w2##i_.y, acc2);                      \
    ha_ = hv_.z * al2; acc0 = fmaf(ha_, w0##i_.z, acc0);                      \
                       acc1 = fmaf(ha_, w1##i_.z, acc1);                      \
                       acc2 = fmaf(ha_, w2##i_.z, acc2);                      \
    ha_ = hv_.w * al3; acc0 = fmaf(ha_, w0##i_.w, acc0);                      \
                       acc1 = fmaf(ha_, w1##i_.w, acc1);                      \
                       acc2 = fmaf(ha_, w2##i_.w, acc2);                      \
} while (0)

// ---- consume buffer S for query g_: softmax, accumulate, reduce, store ----
#define COMPUTE(S, g_) do {                                                   \
    const float geo_   = fmaxf(sqrtf(cv##S.x * cv##S.y), 1e-10f);             \
    const float log_s_ = log_2_over_inp - __logf(geo_);                       \
    const float tau_   = fminf(fmaxf(seven_over_log30 * log_s_, 0.0f), 7.0f); \
    const float d0_ = 0.0f - tau_, d1_ = 1.0f - tau_, d2_ = 2.0f - tau_,      \
                d3_ = 3.0f - tau_, d4_ = 4.0f - tau_, d5_ = 5.0f - tau_,      \
                d6_ = 6.0f - tau_, d7_ = 7.0f - tau_;                         \
    const float ek0 = __expf(-d0_*d0_*inv2s2), ek1 = __expf(-d1_*d1_*inv2s2), \
                ek2 = __expf(-d2_*d2_*inv2s2), ek3 = __expf(-d3_*d3_*inv2s2), \
                ek4 = __expf(-d4_*d4_*inv2s2), ek5 = __expf(-d5_*d5_*inv2s2), \
                ek6 = __expf(-d6_*d6_*inv2s2), ek7 = __expf(-d7_*d7_*inv2s2); \
    const float inv_ = 1.0f / (ek0+ek1+ek2+ek3+ek4+ek5+ek6+ek7);              \
    const float al0 = (odd ? ek4 : ek0) * inv_;                               \
    const float al1 = (odd ? ek5 : ek1) * inv_;                               \
    const float al2 = (odd ? ek6 : ek2) * inv_;                               \
    const float al3 = (odd ? ek7 : ek3) * inv_;                               \
    /* wave-uniform bias term: sum_k alpha_k * bias[k][o], bias in SGPRs */   \
    float bt0 = ek0*sb00; bt0 = fmaf(ek1,sb10,bt0); bt0 = fmaf(ek2,sb20,bt0); \
    bt0 = fmaf(ek3,sb30,bt0); bt0 = fmaf(ek4,sb40,bt0);                       \
    bt0 = fmaf(ek5,sb50,bt0); bt0 = fmaf(ek6,sb60,bt0);                       \
    bt0 = fmaf(ek7,sb70,bt0); bt0 *= inv_;                                    \
    float bt1 = ek0*sb01; bt1 = fmaf(ek1,sb11,bt1); bt1 = fmaf(ek2,sb21,bt1); \
    bt1 = fmaf(ek3,sb31,bt1); bt1 = fmaf(ek4,sb41,bt1);                       \
    bt1 = fmaf(ek5,sb51,bt1); bt1 = fmaf(ek6,sb61,bt1);                       \
    bt1 = fmaf(ek7,sb71,bt1); bt1 *= inv_;                                    \
    float bt2 = ek0*sb02; bt2 = fmaf(ek1,sb12,bt2); bt2 = fmaf(ek2,sb22,bt2); \
    bt2 = fmaf(ek3,sb32,bt2); bt2 = fmaf(ek4,sb42,bt2);                       \
    bt2 = fmaf(ek5,sb52,bt2); bt2 = fmaf(ek6,sb62,bt2);                       \
    bt2 = fmaf(ek7,sb72,bt2); bt2 *= inv_;                                    \
    float acc0 = 0.0f, acc1 = 0.0f, acc2 = 0.0f;                              \
    ACCI(h##S##0, 0);  ACCI(h##S##1, 1);                                      \
    ACCI(h##S##2, 2);  ACCI(h##S##3, 3);                                      \
    _Pragma("unroll") for (int off = 32; off > 0; off >>= 1) {                \
        acc0 += __shfl_xor(acc0, off, 64);                                    \
        acc1 += __shfl_xor(acc1, off, 64);                                    \
        acc2 += __shfl_xor(acc2, off, 64);                                    \
    }                                                                         \
    acc0 += bt0; acc1 += bt1; acc2 += bt2;                                    \
    if (lane < 3) {                                                           \
        const float v_ = (lane == 0) ? acc0 : ((lane == 1) ? acc1 : acc2);    \
        out[(size_t)(g_) * 3 + lane] = v_;                                    \
    }                                                                         \
} while (0)

__global__ __launch_bounds__(NTHREADS, 4)
void gsr_kernel(const float* __restrict__ h,      // [BQ, C_H, K]
                const float* __restrict__ cell,   // [BQ, 2]
                const float* __restrict__ w,      // [K, 3, C_H]
                const float* __restrict__ bias,   // [K, 3]
                float* __restrict__ out,          // [BQ, 3]
                int bq)
{
    const int lane   = threadIdx.x & 63;
    const int waveId = blockIdx.x * (NTHREADS / 64) + (threadIdx.x >> 6);
    if (waveId >= bq) return;

    const int  kbase = (lane & 1) * 4;   // this lane's k-subset base (0 or 4)
    const int  ci    = lane >> 1;        // c within each 32-plane
    const bool odd   = (lane & 1);

    // ---- one-time weight preload: 12 named float4s (48 VGPRs), no arrays ----
#define LDW(o_, i_) make_float4(                                              \
        w[(kbase+0)*(3*C_H) + (o_)*C_H + ((i_)*32+ci)],                       \
        w[(kbase+1)*(3*C_H) + (o_)*C_H + ((i_)*32+ci)],                       \
        w[(kbase+2)*(3*C_H) + (o_)*C_H + ((i_)*32+ci)],                       \
        w[(kbase+3)*(3*C_H) + (o_)*C_H + ((i_)*32+ci)])
    const float4 w00 = LDW(0,0), w01 = LDW(0,1), w02 = LDW(0,2), w03 = LDW(0,3);
    const float4 w10 = LDW(1,0), w11 = LDW(1,1), w12 = LDW(1,2), w13 = LDW(1,3);
    const float4 w20 = LDW(2,0), w21 = LDW(2,1), w22 = LDW(2,2), w23 = LDW(2,3);
#undef LDW

    // ---- bias into SGPRs (uniform): sb{k}{o} ----
#define LDB(k_, o_) rfl(bias[(k_)*3 + (o_)])
    const float sb00=LDB(0,0), sb01=LDB(0,1), sb02=LDB(0,2);
    const float sb10=LDB(1,0), sb11=LDB(1,1), sb12=LDB(1,2);
    const float sb20=LDB(2,0), sb21=LDB(2,1), sb22=LDB(2,2);
    const float sb30=LDB(3,0), sb31=LDB(3,1), sb32=LDB(3,2);
    const float sb40=LDB(4,0), sb41=LDB(4,1), sb42=LDB(4,2);
    const float sb50=LDB(5,0), sb51=LDB(5,1), sb52=LDB(5,2);
    const float sb60=LDB(6,0), sb61=LDB(6,1), sb62=LDB(6,2);
    const float sb70=LDB(7,0), sb71=LDB(7,1), sb72=LDB(7,2);
#undef LDB

    const float inv2s2           = 0.78125f;             // 1 / (2*0.8^2)
    const float log_2_over_inp   = -4.8520302639196171f; // log(2/256)
    const float seven_over_log30 = 2.0580814087539097f;  // 7 / log(30)

    const float2* cell2 = (const float2*)cell;

    // ---- pipeline state: pure named scalars, guaranteed registers ----
    float2 cvA, cvB;
    float4 hA0, hA1, hA2, hA3;
    float4 hB0, hB1, hB2, hB3;

    int g  = waveId;
    ISSUE(A, g);
    int gn = g + NWAVES;
    while (true) {
        if (gn >= bq) { COMPUTE(A, g); break; }
        ISSUE(B, gn);                 // batch n+1 in flight across compute of n
        COMPUTE(A, g);
        g = gn;  gn += NWAVES;
        if (gn >= bq) { COMPUTE(B, g); break; }
        ISSUE(A, gn);
        COMPUTE(B, g);
        g = gn;  gn += NWAVES;
    }
}

extern "C" void kernel_launch(void* const* d_in, const int* in_sizes, int n_in,
                              void* d_out, int out_size, void* d_ws, size_t ws_size,
                              hipStream_t stream) {
    const float* h    = (const float*)d_in[0];
    const float* cell = (const float*)d_in[1];
    const float* w    = (const float*)d_in[2];
    const float* bias = (const float*)d_in[3];
    float* out = (float*)d_out;
    const int bq = in_sizes[0] / (C_H * KSC);

    gsr_kernel<<<NBLOCKS, NTHREADS, 0, stream>>>(h, cell, w, bias, out, bq);
}